// Round 6
// baseline (321.440 us; speedup 1.0000x reference)
//
#include <hip/hip_runtime.h>
#include <hip/hip_bf16.h>

// Problem constants (fixed by the reference): B=16, V=8192, N=2048, H=128, C_OUT=7
#define B_GR   16
#define V_PTS  8192
#define N_RES  2048
#define H_DIM  128
#define C_OUT  7
#define SEGS   16            // pool kernel: residue segments per graph (128 residues each)
#define NB     512           // x-buckets for pruned search
#define CPAD   520           // padded per-graph cellstart stride

// Ledger: r1 pk-f32 not double-rate; r2 occupancy-insensitive (issue-bound);
// r3 atomics free; r4 per-n amortization ~nil; r5 LDS pipelining nil, node
// overhead nil. Brute argmin pinned at 59-61 µs ~= chip's effective VALU
// ceiling for the mandatory 10-op bit-exact sequence. r6: algorithmic cut —
// bucket-pruned exact search evaluates ~300-500 candidates/vertex instead of
// 2048, with margin-safe slab bounds and lexicographic (d, idx) selection.

// exact bucket function (identical in prep & search)
__device__ __forceinline__ int bucketof(float x) {
    int bk = (int)floorf((x + 52.0f) * (512.0f / 104.0f));
    return bk < 0 ? 0 : (bk > NB - 1 ? NB - 1 : bk);
}

// one candidate: bit-exact reference sequence + lexicographic (d, orig idx)
__device__ __forceinline__ void eval_one(const float4 c, int id,
                                         float vx, float vy, float vz, float vsq,
                                         float& best, int& bidx) {
    float dot = __fadd_rn(__fadd_rn(__fmul_rn(vx, c.x), __fmul_rn(vy, c.y)),
                          __fmul_rn(vz, c.z));
    float d = __fadd_rn(fmaf(-2.0f, dot, vsq), c.w);
    bool take = (d < best) || ((d == best) && (id < bidx));
    best = take ? d : best;
    bidx = take ? id : bidx;
}

// ---------------------------------------------------------------------------
// Kernel 0 (prep): per graph — counting-sort residues by x-bucket into a
// contiguous sorted array (float4 x,y,z,csq + orig idx), write exclusive
// bucket starts, zero the hit mask. csq uses the exact reference sequence.
// Within-bucket order is arbitrary (LDS atomic order) — harmless, selection
// is lexicographic. 16 blocks x 256 threads.
// ---------------------------------------------------------------------------
__global__ __launch_bounds__(256) void k_prep(const float* __restrict__ coords,
                                              float4* __restrict__ sf4g,
                                              unsigned int* __restrict__ sidxg,
                                              unsigned int* __restrict__ cellsg,
                                              float* __restrict__ msk) {
    __shared__ unsigned int hist[NB];
    __shared__ unsigned int sA[NB], sB[NB];
    __shared__ unsigned int cursor[NB];
    const int b = blockIdx.x;
    const int tid = threadIdx.x;

    for (int i = tid; i < NB; i += 256) hist[i] = 0;
    for (int i = tid; i < N_RES; i += 256) msk[b * N_RES + i] = 0.0f;
    __syncthreads();

    const float* cb = coords + (size_t)b * N_RES * 3;
    for (int i = tid; i < N_RES; i += 256)
        atomicAdd(&hist[bucketof(cb[i * 3])], 1u);
    __syncthreads();

    for (int i = tid; i < NB; i += 256) sA[i] = hist[i];
    __syncthreads();
    unsigned int* src = sA;
    unsigned int* dst = sB;
    for (int off = 1; off < NB; off <<= 1) {            // Hillis-Steele inclusive
        for (int i = tid; i < NB; i += 256)
            dst[i] = src[i] + (i >= off ? src[i - off] : 0u);
        __syncthreads();
        unsigned int* t = src; src = dst; dst = t;
    }
    for (int i = tid; i < NB; i += 256) {
        unsigned int ex = src[i] - hist[i];             // exclusive start
        cellsg[b * CPAD + i] = ex;
        cursor[i] = ex;
    }
    if (tid == 0) cellsg[b * CPAD + NB] = N_RES;
    __syncthreads();

    for (int i = tid; i < N_RES; i += 256) {
        float x = cb[i * 3 + 0];
        float y = cb[i * 3 + 1];
        float z = cb[i * 3 + 2];
        float csq = __fadd_rn(__fadd_rn(__fmul_rn(x, x), __fmul_rn(y, y)), __fmul_rn(z, z));
        unsigned int pos = atomicAdd(&cursor[bucketof(x)], 1u);
        sf4g[(size_t)b * N_RES + pos] = make_float4(x, y, z, csq);
        sidxg[(size_t)b * N_RES + pos] = (unsigned int)i;
    }
}

// ---------------------------------------------------------------------------
// Kernel 1 (search): one thread per vertex. Stage the graph's bucket-sorted
// residues in LDS (36 KB). Phase 1: evaluate a 32-candidate window near the
// vertex's own bucket -> upper bound `best`. Phase 2: flat-scan the bucket
// range covering [x-W, x+W], W = sqrt(best+1)+1/16. Margin M=1.0 >> the
// <=4e-3 worst-case |d_exact - d_true| cancellation error, so every residue
// whose exact d could win (or tie) lies inside the slab; the lexicographic
// compare reproduces np.argmin first-occurrence exactly. Winner scattered
// into the hit mask (race-benign 1.0f). 512 blocks x 256 threads.
// ---------------------------------------------------------------------------
__global__ __launch_bounds__(256) void k_search(const float* __restrict__ verts,
                                                const float4* __restrict__ sf4g,
                                                const unsigned int* __restrict__ sidxg,
                                                const unsigned int* __restrict__ cellsg,
                                                float* __restrict__ msk) {
    __shared__ float4 sf4[N_RES];                       // 32 KB
    __shared__ unsigned short sidx[N_RES];              // 4 KB
    __shared__ unsigned short cs[NB + 1];               // 1 KB
    const int b     = blockIdx.x >> 5;                  // 32 blocks per graph
    const int chunk = blockIdx.x & 31;

    for (int i = threadIdx.x; i < N_RES; i += 256) {
        sf4[i]  = sf4g[(size_t)b * N_RES + i];
        sidx[i] = (unsigned short)sidxg[(size_t)b * N_RES + i];
    }
    for (int i = threadIdx.x; i < NB + 1; i += 256)
        cs[i] = (unsigned short)cellsg[b * CPAD + i];
    __syncthreads();

    const int v = chunk * 256 + threadIdx.x;
    const float* vp = verts + ((size_t)b * V_PTS + v) * 3;
    const float vx = vp[0], vy = vp[1], vz = vp[2];
    const float vsq = __fadd_rn(__fadd_rn(__fmul_rn(vx, vx), __fmul_rn(vy, vy)),
                                __fmul_rn(vz, vz));

    float best = 3.402823466e+38f;
    int bidx = 1 << 30;

    // phase 1: 32-candidate seed window around own bucket start
    {
        int j0 = cs[bucketof(vx)];
        int lo = j0 - 16;
        lo = lo < 0 ? 0 : (lo > N_RES - 32 ? N_RES - 32 : lo);
#pragma unroll 4
        for (int j = lo; j < lo + 32; ++j)
            eval_one(sf4[j], (int)sidx[j], vx, vy, vz, vsq, best, bidx);
    }

    // phase 2: slab scan (window re-evaluated inside; idempotent under lex)
    const float W = sqrtf(best + 1.0f) + 0.0625f;
    const int bklo = bucketof(vx - W);
    const int bkhi = bucketof(vx + W);
    const int jlo = cs[bklo];
    const int jhi = cs[bkhi + 1];
#pragma unroll 4
    for (int j = jlo; j < jhi; ++j)
        eval_one(sf4[j], (int)sidx[j], vx, vy, vz, vsq, best, bidx);

    msk[b * N_RES + bidx] = 1.0f;                       // orig residue index
}

// ---------------------------------------------------------------------------
// Kernel 2: masked-sum a 128-residue slice of feats with float4 loads; mask
// slice staged from the tiny global msk array. B*SEGS = 256 blocks.
// ---------------------------------------------------------------------------
__global__ __launch_bounds__(256) void k_pool_m(const float* __restrict__ msk,
                                                const float* __restrict__ feats,
                                                float* __restrict__ partial) {
    __shared__ float sm[N_RES / SEGS];                  // 512 B mask slice
    __shared__ float4 red[8][32];
    const int b   = blockIdx.x >> 4;
    const int seg = blockIdx.x & (SEGS - 1);
    const int n0  = seg * (N_RES / SEGS);

    if (threadIdx.x < N_RES / SEGS) sm[threadIdx.x] = msk[b * N_RES + n0 + threadIdx.x];
    __syncthreads();

    const int q = threadIdx.x & 31;                     // float4 column (h = 4q..4q+3)
    const int s = threadIdx.x >> 5;                     // n-slice 0..7
    const float4* fb4 = (const float4*)(feats + ((size_t)b * N_RES + n0) * H_DIM);

    float4 acc = make_float4(0.f, 0.f, 0.f, 0.f);
#pragma unroll
    for (int n = 0; n < N_RES / SEGS / 8; ++n) {
        const int nn = s + n * 8;
        const float m = sm[nn];
        const float4 f = fb4[(size_t)nn * 32 + q];
        acc.x = fmaf(f.x, m, acc.x);
        acc.y = fmaf(f.y, m, acc.y);
        acc.z = fmaf(f.z, m, acc.z);
        acc.w = fmaf(f.w, m, acc.w);
    }
    red[s][q] = acc;
    __syncthreads();

    if (s == 0) {
        float4 t = acc;
#pragma unroll
        for (int i = 1; i < 8; ++i) {
            t.x += red[i][q].x; t.y += red[i][q].y;
            t.z += red[i][q].z; t.w += red[i][q].w;
        }
        ((float4*)partial)[((size_t)b * SEGS + seg) * 32 + q] = t;
    }
}

// ---------------------------------------------------------------------------
// Fallback path (small workspace): brute-force atomicMin kernels (r0).
// ---------------------------------------------------------------------------
#define NSPLIT 16
#define NL     (N_RES / NSPLIT)
#define FVPT   8
#define FVBLK  (256 * FVPT)
#define FVBLKS (V_PTS / FVBLK)
__global__ __launch_bounds__(256, 4) void k_argmin_at(const float* __restrict__ verts,
                                                      const float* __restrict__ coords,
                                                      unsigned long long* __restrict__ mi64) {
    __shared__ float4 sc[NL];
    const int b  = blockIdx.x / (FVBLKS * NSPLIT);
    const int r  = blockIdx.x % (FVBLKS * NSPLIT);
    const int vb = r / NSPLIT;
    const int ns = r % NSPLIT;

    const float* cbase = coords + ((size_t)b * N_RES + ns * NL) * 3;
    if (threadIdx.x < NL) {
        const int i = threadIdx.x;
        float x = cbase[i * 3 + 0];
        float y = cbase[i * 3 + 1];
        float z = cbase[i * 3 + 2];
        float csq = __fadd_rn(__fadd_rn(__fmul_rn(x, x), __fmul_rn(y, y)), __fmul_rn(z, z));
        sc[i] = make_float4(x, y, z, csq);
    }
    __syncthreads();

    const int vbase = vb * FVBLK + threadIdx.x;
    const float* vp = verts + (size_t)b * V_PTS * 3;

    float vx[FVPT], vy[FVPT], vz[FVPT], vsq[FVPT], best[FVPT];
    int bi[FVPT];
#pragma unroll
    for (int k = 0; k < FVPT; ++k) {
        const int v = vbase + k * 256;
        vx[k] = vp[v * 3 + 0];
        vy[k] = vp[v * 3 + 1];
        vz[k] = vp[v * 3 + 2];
        vsq[k] = __fadd_rn(__fadd_rn(__fmul_rn(vx[k], vx[k]), __fmul_rn(vy[k], vy[k])),
                           __fmul_rn(vz[k], vz[k]));
        best[k] = 3.402823466e+38f;
        bi[k] = 0;
    }
#pragma unroll 2
    for (int n = 0; n < NL; ++n) {
        const float4 c = sc[n];
#pragma unroll
        for (int k = 0; k < FVPT; ++k) {
            float dot = __fadd_rn(__fadd_rn(__fmul_rn(vx[k], c.x), __fmul_rn(vy[k], c.y)),
                                  __fmul_rn(vz[k], c.z));
            float d = __fadd_rn(fmaf(-2.0f, dot, vsq[k]), c.w);
            bool m = d < best[k];
            best[k] = m ? d : best[k];
            bi[k]   = m ? n : bi[k];
        }
    }
#pragma unroll
    for (int k = 0; k < FVPT; ++k) {
        unsigned int bits = __float_as_uint(best[k]);
        unsigned int key  = bits ^ (unsigned int)(((int)bits >> 31) | 0x80000000);
        unsigned long long packed =
            ((unsigned long long)key << 32) | (unsigned int)(ns * NL + bi[k]);
        atomicMin(&mi64[(size_t)b * V_PTS + vbase + k * 256], packed);
    }
}

__global__ __launch_bounds__(256) void k_pool_at(const unsigned long long* __restrict__ mi64,
                                                 const float* __restrict__ feats,
                                                 float* __restrict__ partial) {
    __shared__ float msk[N_RES];
    __shared__ float4 red[8][32];
    const int b   = blockIdx.x >> 4;
    const int seg = blockIdx.x & (SEGS - 1);

    for (int i = threadIdx.x; i < N_RES; i += 256) msk[i] = 0.0f;
    __syncthreads();
    const unsigned long long* mb = mi64 + (size_t)b * V_PTS;
    for (int v = threadIdx.x; v < V_PTS; v += 256)
        msk[(unsigned int)mb[v]] = 1.0f;
    __syncthreads();

    const int q = threadIdx.x & 31;
    const int s = threadIdx.x >> 5;
    const int n0 = seg * (N_RES / SEGS);
    const float4* fb4 = (const float4*)(feats + ((size_t)b * N_RES + n0) * H_DIM);

    float4 acc = make_float4(0.f, 0.f, 0.f, 0.f);
#pragma unroll
    for (int n = 0; n < N_RES / SEGS / 8; ++n) {
        const int nn = s + n * 8;
        const float m = msk[n0 + nn];
        const float4 f = fb4[(size_t)nn * 32 + q];
        acc.x = fmaf(f.x, m, acc.x);
        acc.y = fmaf(f.y, m, acc.y);
        acc.z = fmaf(f.z, m, acc.z);
        acc.w = fmaf(f.w, m, acc.w);
    }
    red[s][q] = acc;
    __syncthreads();
    if (s == 0) {
        float4 t = acc;
#pragma unroll
        for (int i = 1; i < 8; ++i) {
            t.x += red[i][q].x; t.y += red[i][q].y;
            t.z += red[i][q].z; t.w += red[i][q].w;
        }
        ((float4*)partial)[((size_t)b * SEGS + seg) * 32 + q] = t;
    }
}

// ---------------------------------------------------------------------------
// Kernel 3: per-graph block — reduce 16 seg partials -> pooled[H], then
// relu(pooled@W1+b1)@W2+b2 -> out[b][7]. 16 blocks x 128 threads.
// (r1 lesson: last-block-done fusion costs ~19 µs via device-scope
// threadfence on non-coherent XCD L2s. Separate tiny launch is cheaper.)
// ---------------------------------------------------------------------------
__global__ __launch_bounds__(128) void k_mlp(const float* __restrict__ partial,
                                             const float* __restrict__ W1,
                                             const float* __restrict__ b1,
                                             const float* __restrict__ W2,
                                             const float* __restrict__ b2,
                                             float* __restrict__ out) {
    __shared__ float pooled[H_DIM];
    __shared__ float h1[H_DIM];
    const int b = blockIdx.x;
    const int j = threadIdx.x;

    float s = 0.0f;
#pragma unroll
    for (int g = 0; g < SEGS; ++g)
        s += partial[((size_t)b * SEGS + g) * H_DIM + j];
    pooled[j] = s;
    __syncthreads();

    float acc = b1[j];
#pragma unroll 8
    for (int hh = 0; hh < H_DIM; ++hh)
        acc = fmaf(pooled[hh], W1[hh * H_DIM + j], acc);
    h1[j] = fmaxf(acc, 0.0f);
    __syncthreads();

    if (j < C_OUT) {
        float o = b2[j];
#pragma unroll 8
        for (int hh = 0; hh < H_DIM; ++hh)
            o = fmaf(h1[hh], W2[hh * C_OUT + j], o);
        out[(size_t)b * C_OUT + j] = o;
    }
}

extern "C" void kernel_launch(void* const* d_in, const int* in_sizes, int n_in,
                              void* d_out, int out_size, void* d_ws, size_t ws_size,
                              hipStream_t stream) {
    const float* verts  = (const float*)d_in[0];   // [B,V,3]
    const float* coords = (const float*)d_in[1];   // [B,N,3]
    const float* feats  = (const float*)d_in[2];   // [B,N,H]
    const float* W1     = (const float*)d_in[3];   // [H,H]
    const float* b1     = (const float*)d_in[4];   // [H]
    const float* W2     = (const float*)d_in[5];   // [H,C_OUT]
    const float* b2     = (const float*)d_in[6];   // [C_OUT]
    float* out = (float*)d_out;                    // [B,C_OUT]

    // workspace layout (pruned path, ~930 KB total)
    const size_t sf4_bytes  = (size_t)B_GR * N_RES * 16;   // 512 KB, offset 0 (16B aligned)
    const size_t sidx_bytes = (size_t)B_GR * N_RES * 4;    // 128 KB
    const size_t cell_bytes = (size_t)B_GR * CPAD * 4;     // ~33 KB
    const size_t msk_bytes  = (size_t)B_GR * N_RES * 4;    // 128 KB
    const size_t pp_bytes   = (size_t)B_GR * SEGS * H_DIM * 4; // 128 KB
    const size_t need = sf4_bytes + sidx_bytes + cell_bytes + msk_bytes + pp_bytes;

    if (ws_size >= need) {
        float4*       sf4g  = (float4*)d_ws;
        unsigned int* sidxg = (unsigned int*)((char*)d_ws + sf4_bytes);
        unsigned int* cells = (unsigned int*)((char*)d_ws + sf4_bytes + sidx_bytes);
        float* msk     = (float*)((char*)d_ws + sf4_bytes + sidx_bytes + cell_bytes);
        float* partial = (float*)((char*)d_ws + sf4_bytes + sidx_bytes + cell_bytes + msk_bytes);

        k_prep  <<<B_GR,              256, 0, stream>>>(coords, sf4g, sidxg, cells, msk);
        k_search<<<B_GR * V_PTS / 256, 256, 0, stream>>>(verts, sf4g, sidxg, cells, msk);
        k_pool_m<<<B_GR * SEGS,       256, 0, stream>>>(msk, feats, partial);
        k_mlp   <<<B_GR,              128, 0, stream>>>(partial, W1, b1, W2, b2, out);
    } else {
        // ---- fallback: brute-force atomicMin path ----
        unsigned long long* mi64 = (unsigned long long*)d_ws;              // 1 MB
        float* partial = (float*)((char*)d_ws + (size_t)B_GR * V_PTS * 8); // 128 KB

        hipMemsetAsync(mi64, 0xFF, (size_t)B_GR * V_PTS * 8, stream);
        k_argmin_at<<<B_GR * FVBLKS * NSPLIT, 256, 0, stream>>>(verts, coords, mi64);
        k_pool_at  <<<B_GR * SEGS,            256, 0, stream>>>(mi64, feats, partial);
        k_mlp      <<<B_GR,                   128, 0, stream>>>(partial, W1, b1, W2, b2, out);
    }
}

// Round 7
// 312.969 us; speedup vs baseline: 1.0271x; 1.0271x over previous
//
#include <hip/hip_runtime.h>
#include <hip/hip_bf16.h>

// Problem constants (fixed by the reference): B=16, V=8192, N=2048, H=128, C_OUT=7
#define B_GR   16
#define V_PTS  8192
#define N_RES  2048
#define H_DIM  128
#define C_OUT  7
#define SEGS   16            // pool kernel: residue segments per graph (128 residues each)
#define NB     512           // x-buckets for pruned search
#define CPAD   520           // padded per-graph cellstart stride

// Ledger: r1 pk-f32 not double-rate; r2 issue-bound not latency-bound; r3
// atomics free; r4 per-n amortization nil; r5 LDS pipelining nil; r6 pruned
// search CORRECT (absmax 0) but per-lane random ds_read_b128 = 1.25e7 bank
// conflicts + divergent ranges -> 241 µs. r7: sort VERTICES by x too; wave
// holds adjacent-x vertices -> wave-union uniform scan range + broadcast
// sf4[j] reads (zero conflicts, zero divergence).

// exact bucket function (identical in prep & search)
__device__ __forceinline__ int bucketof(float x) {
    int bk = (int)floorf((x + 52.0f) * (512.0f / 104.0f));
    return bk < 0 ? 0 : (bk > NB - 1 ? NB - 1 : bk);
}

// one candidate: bit-exact reference sequence + lexicographic (d, orig idx)
__device__ __forceinline__ void eval_one(const float4 c, int id,
                                         float vx, float vy, float vz, float vsq,
                                         float& best, int& bidx) {
    float dot = __fadd_rn(__fadd_rn(__fmul_rn(vx, c.x), __fmul_rn(vy, c.y)),
                          __fmul_rn(vz, c.z));
    float d = __fadd_rn(fmaf(-2.0f, dot, vsq), c.w);
    bool take = (d < best) || ((d == best) && (id < bidx));
    best = take ? d : best;
    bidx = take ? id : bidx;
}

__device__ __forceinline__ int wave_imin(int v) {
#pragma unroll
    for (int o = 1; o < 64; o <<= 1) { int t = __shfl_xor(v, o); v = t < v ? t : v; }
    return __builtin_amdgcn_readfirstlane(v);
}
__device__ __forceinline__ int wave_imax(int v) {
#pragma unroll
    for (int o = 1; o < 64; o <<= 1) { int t = __shfl_xor(v, o); v = t > v ? t : v; }
    return __builtin_amdgcn_readfirstlane(v);
}

// ---------------------------------------------------------------------------
// Kernel 0 (prep): per graph — counting-sort RESIDUES by x-bucket into
// (float4 x,y,z,csq + orig idx u32) + exclusive bucket starts; counting-sort
// VERTICES by x-bucket into float4 (x,y,z,vsq); zero the hit mask. All
// squared-norms use the exact reference fp sequence. Within-bucket order is
// arbitrary (LDS atomic order) — harmless, selection is lexicographic and
// vertex order is irrelevant (only the hit mask matters).
// 16 blocks x 256 threads.
// ---------------------------------------------------------------------------
__global__ __launch_bounds__(256) void k_prep(const float* __restrict__ coords,
                                              const float* __restrict__ verts,
                                              float4* __restrict__ sf4g,
                                              unsigned int* __restrict__ sidxg,
                                              unsigned int* __restrict__ cellsg,
                                              float4* __restrict__ vf4g,
                                              float* __restrict__ msk) {
    __shared__ unsigned int hist[NB];
    __shared__ unsigned int sA[NB], sB[NB];
    __shared__ unsigned int cursor[NB];
    const int b = blockIdx.x;
    const int tid = threadIdx.x;

    // ---- residues ----
    for (int i = tid; i < NB; i += 256) hist[i] = 0;
    for (int i = tid; i < N_RES; i += 256) msk[b * N_RES + i] = 0.0f;
    __syncthreads();

    const float* cb = coords + (size_t)b * N_RES * 3;
    for (int i = tid; i < N_RES; i += 256)
        atomicAdd(&hist[bucketof(cb[i * 3])], 1u);
    __syncthreads();

    for (int i = tid; i < NB; i += 256) sA[i] = hist[i];
    __syncthreads();
    unsigned int* src = sA;
    unsigned int* dst = sB;
    for (int off = 1; off < NB; off <<= 1) {            // Hillis-Steele inclusive
        for (int i = tid; i < NB; i += 256)
            dst[i] = src[i] + (i >= off ? src[i - off] : 0u);
        __syncthreads();
        unsigned int* t = src; src = dst; dst = t;
    }
    for (int i = tid; i < NB; i += 256) {
        unsigned int ex = src[i] - hist[i];             // exclusive start
        cellsg[b * CPAD + i] = ex;
        cursor[i] = ex;
    }
    if (tid == 0) cellsg[b * CPAD + NB] = N_RES;
    __syncthreads();

    for (int i = tid; i < N_RES; i += 256) {
        float x = cb[i * 3 + 0];
        float y = cb[i * 3 + 1];
        float z = cb[i * 3 + 2];
        float csq = __fadd_rn(__fadd_rn(__fmul_rn(x, x), __fmul_rn(y, y)), __fmul_rn(z, z));
        unsigned int pos = atomicAdd(&cursor[bucketof(x)], 1u);
        sf4g[(size_t)b * N_RES + pos] = make_float4(x, y, z, csq);
        sidxg[(size_t)b * N_RES + pos] = (unsigned int)i;
    }
    __syncthreads();

    // ---- vertices (reuse hist/scan/cursor) ----
    for (int i = tid; i < NB; i += 256) hist[i] = 0;
    __syncthreads();
    const float* vb = verts + (size_t)b * V_PTS * 3;
    for (int i = tid; i < V_PTS; i += 256)
        atomicAdd(&hist[bucketof(vb[i * 3])], 1u);
    __syncthreads();
    for (int i = tid; i < NB; i += 256) sA[i] = hist[i];
    __syncthreads();
    src = sA; dst = sB;
    for (int off = 1; off < NB; off <<= 1) {
        for (int i = tid; i < NB; i += 256)
            dst[i] = src[i] + (i >= off ? src[i - off] : 0u);
        __syncthreads();
        unsigned int* t = src; src = dst; dst = t;
    }
    for (int i = tid; i < NB; i += 256)
        cursor[i] = src[i] - hist[i];
    __syncthreads();
    for (int i = tid; i < V_PTS; i += 256) {
        float x = vb[i * 3 + 0];
        float y = vb[i * 3 + 1];
        float z = vb[i * 3 + 2];
        float vsq = __fadd_rn(__fadd_rn(__fmul_rn(x, x), __fmul_rn(y, y)), __fmul_rn(z, z));
        unsigned int pos = atomicAdd(&cursor[bucketof(x)], 1u);
        vf4g[(size_t)b * V_PTS + pos] = make_float4(x, y, z, vsq);
    }
}

// ---------------------------------------------------------------------------
// Kernel 1 (search): one thread per SORTED vertex (lanes hold adjacent-x
// vertices). Stage the graph's bucket-sorted residues in LDS. Phase 1:
// wave-uniform 32+spread seed window near the wave's buckets -> upper bound.
// Phase 2: per-lane slab [x-W, x+W], W = sqrt(best+1)+1/16, wave-union range
// scanned uniformly — every lane reads the SAME sf4[j] (LDS broadcast, no
// bank conflicts, no divergence). Margin 1.0 >> 4e-3 worst-case cancellation
// error, so no true argmin (or exact tie) can be outside the slab; the
// lexicographic (d, orig idx) compare reproduces np.argmin first-occurrence
// exactly (validated r6: absmax 0). Winner -> hit mask (race-benign 1.0f).
// 512 blocks x 256 threads.
// ---------------------------------------------------------------------------
__global__ __launch_bounds__(256) void k_search(const float4* __restrict__ vf4g,
                                                const float4* __restrict__ sf4g,
                                                const unsigned int* __restrict__ sidxg,
                                                const unsigned int* __restrict__ cellsg,
                                                float* __restrict__ msk) {
    __shared__ float4 sf4[N_RES];                       // 32 KB
    __shared__ unsigned short sidx[N_RES];              // 4 KB
    __shared__ unsigned short cs[NB + 1];               // ~1 KB
    const int b     = blockIdx.x >> 5;                  // 32 blocks per graph
    const int chunk = blockIdx.x & 31;

    for (int i = threadIdx.x; i < N_RES; i += 256) {
        sf4[i]  = sf4g[(size_t)b * N_RES + i];
        sidx[i] = (unsigned short)sidxg[(size_t)b * N_RES + i];
    }
    for (int i = threadIdx.x; i < NB + 1; i += 256)
        cs[i] = (unsigned short)cellsg[b * CPAD + i];
    __syncthreads();

    const float4 vv = vf4g[(size_t)b * V_PTS + chunk * 256 + threadIdx.x];
    const float vx = vv.x, vy = vv.y, vz = vv.z, vsq = vv.w;

    float best = 3.402823466e+38f;
    int bidx = 1 << 30;

    // phase 1: wave-uniform seed window (union of per-lane 32-windows;
    // lanes are adjacent in x so the union is ~32-48 candidates)
    {
        int lo = (int)cs[bucketof(vx)] - 16;
        lo = lo < 0 ? 0 : (lo > N_RES - 32 ? N_RES - 32 : lo);
        const int slo = wave_imin(lo);
        const int shi = wave_imax(lo) + 32;
#pragma unroll 2
        for (int j = slo; j < shi; ++j)
            eval_one(sf4[j], (int)sidx[j], vx, vy, vz, vsq, best, bidx);
    }

    // phase 2: wave-union slab scan, uniform bounds, broadcast reads
    const float W = sqrtf(best + 1.0f) + 0.0625f;
    const int jlo = wave_imin((int)cs[bucketof(vx - W)]);
    const int jhi = wave_imax((int)cs[bucketof(vx + W) + 1]);
#pragma unroll 2
    for (int j = jlo; j < jhi; ++j)
        eval_one(sf4[j], (int)sidx[j], vx, vy, vz, vsq, best, bidx);

    msk[b * N_RES + bidx] = 1.0f;                       // orig residue index
}

// ---------------------------------------------------------------------------
// Kernel 2: masked-sum a 128-residue slice of feats with float4 loads; mask
// slice staged from the tiny global msk array. B*SEGS = 256 blocks.
// ---------------------------------------------------------------------------
__global__ __launch_bounds__(256) void k_pool_m(const float* __restrict__ msk,
                                                const float* __restrict__ feats,
                                                float* __restrict__ partial) {
    __shared__ float sm[N_RES / SEGS];                  // 512 B mask slice
    __shared__ float4 red[8][32];
    const int b   = blockIdx.x >> 4;
    const int seg = blockIdx.x & (SEGS - 1);
    const int n0  = seg * (N_RES / SEGS);

    if (threadIdx.x < N_RES / SEGS) sm[threadIdx.x] = msk[b * N_RES + n0 + threadIdx.x];
    __syncthreads();

    const int q = threadIdx.x & 31;                     // float4 column (h = 4q..4q+3)
    const int s = threadIdx.x >> 5;                     // n-slice 0..7
    const float4* fb4 = (const float4*)(feats + ((size_t)b * N_RES + n0) * H_DIM);

    float4 acc = make_float4(0.f, 0.f, 0.f, 0.f);
#pragma unroll
    for (int n = 0; n < N_RES / SEGS / 8; ++n) {
        const int nn = s + n * 8;
        const float m = sm[nn];
        const float4 f = fb4[(size_t)nn * 32 + q];
        acc.x = fmaf(f.x, m, acc.x);
        acc.y = fmaf(f.y, m, acc.y);
        acc.z = fmaf(f.z, m, acc.z);
        acc.w = fmaf(f.w, m, acc.w);
    }
    red[s][q] = acc;
    __syncthreads();

    if (s == 0) {
        float4 t = acc;
#pragma unroll
        for (int i = 1; i < 8; ++i) {
            t.x += red[i][q].x; t.y += red[i][q].y;
            t.z += red[i][q].z; t.w += red[i][q].w;
        }
        ((float4*)partial)[((size_t)b * SEGS + seg) * 32 + q] = t;
    }
}

// ---------------------------------------------------------------------------
// Fallback path (small workspace): brute-force atomicMin kernels (r0).
// ---------------------------------------------------------------------------
#define NSPLIT 16
#define NL     (N_RES / NSPLIT)
#define FVPT   8
#define FVBLK  (256 * FVPT)
#define FVBLKS (V_PTS / FVBLK)
__global__ __launch_bounds__(256, 4) void k_argmin_at(const float* __restrict__ verts,
                                                      const float* __restrict__ coords,
                                                      unsigned long long* __restrict__ mi64) {
    __shared__ float4 sc[NL];
    const int b  = blockIdx.x / (FVBLKS * NSPLIT);
    const int r  = blockIdx.x % (FVBLKS * NSPLIT);
    const int vb = r / NSPLIT;
    const int ns = r % NSPLIT;

    const float* cbase = coords + ((size_t)b * N_RES + ns * NL) * 3;
    if (threadIdx.x < NL) {
        const int i = threadIdx.x;
        float x = cbase[i * 3 + 0];
        float y = cbase[i * 3 + 1];
        float z = cbase[i * 3 + 2];
        float csq = __fadd_rn(__fadd_rn(__fmul_rn(x, x), __fmul_rn(y, y)), __fmul_rn(z, z));
        sc[i] = make_float4(x, y, z, csq);
    }
    __syncthreads();

    const int vbase = vb * FVBLK + threadIdx.x;
    const float* vp = verts + (size_t)b * V_PTS * 3;

    float vx[FVPT], vy[FVPT], vz[FVPT], vsq[FVPT], best[FVPT];
    int bi[FVPT];
#pragma unroll
    for (int k = 0; k < FVPT; ++k) {
        const int v = vbase + k * 256;
        vx[k] = vp[v * 3 + 0];
        vy[k] = vp[v * 3 + 1];
        vz[k] = vp[v * 3 + 2];
        vsq[k] = __fadd_rn(__fadd_rn(__fmul_rn(vx[k], vx[k]), __fmul_rn(vy[k], vy[k])),
                           __fmul_rn(vz[k], vz[k]));
        best[k] = 3.402823466e+38f;
        bi[k] = 0;
    }
#pragma unroll 2
    for (int n = 0; n < NL; ++n) {
        const float4 c = sc[n];
#pragma unroll
        for (int k = 0; k < FVPT; ++k) {
            float dot = __fadd_rn(__fadd_rn(__fmul_rn(vx[k], c.x), __fmul_rn(vy[k], c.y)),
                                  __fmul_rn(vz[k], c.z));
            float d = __fadd_rn(fmaf(-2.0f, dot, vsq[k]), c.w);
            bool m = d < best[k];
            best[k] = m ? d : best[k];
            bi[k]   = m ? n : bi[k];
        }
    }
#pragma unroll
    for (int k = 0; k < FVPT; ++k) {
        unsigned int bits = __float_as_uint(best[k]);
        unsigned int key  = bits ^ (unsigned int)(((int)bits >> 31) | 0x80000000);
        unsigned long long packed =
            ((unsigned long long)key << 32) | (unsigned int)(ns * NL + bi[k]);
        atomicMin(&mi64[(size_t)b * V_PTS + vbase + k * 256], packed);
    }
}

__global__ __launch_bounds__(256) void k_pool_at(const unsigned long long* __restrict__ mi64,
                                                 const float* __restrict__ feats,
                                                 float* __restrict__ partial) {
    __shared__ float msk[N_RES];
    __shared__ float4 red[8][32];
    const int b   = blockIdx.x >> 4;
    const int seg = blockIdx.x & (SEGS - 1);

    for (int i = threadIdx.x; i < N_RES; i += 256) msk[i] = 0.0f;
    __syncthreads();
    const unsigned long long* mb = mi64 + (size_t)b * V_PTS;
    for (int v = threadIdx.x; v < V_PTS; v += 256)
        msk[(unsigned int)mb[v]] = 1.0f;
    __syncthreads();

    const int q = threadIdx.x & 31;
    const int s = threadIdx.x >> 5;
    const int n0 = seg * (N_RES / SEGS);
    const float4* fb4 = (const float4*)(feats + ((size_t)b * N_RES + n0) * H_DIM);

    float4 acc = make_float4(0.f, 0.f, 0.f, 0.f);
#pragma unroll
    for (int n = 0; n < N_RES / SEGS / 8; ++n) {
        const int nn = s + n * 8;
        const float m = msk[n0 + nn];
        const float4 f = fb4[(size_t)nn * 32 + q];
        acc.x = fmaf(f.x, m, acc.x);
        acc.y = fmaf(f.y, m, acc.y);
        acc.z = fmaf(f.z, m, acc.z);
        acc.w = fmaf(f.w, m, acc.w);
    }
    red[s][q] = acc;
    __syncthreads();
    if (s == 0) {
        float4 t = acc;
#pragma unroll
        for (int i = 1; i < 8; ++i) {
            t.x += red[i][q].x; t.y += red[i][q].y;
            t.z += red[i][q].z; t.w += red[i][q].w;
        }
        ((float4*)partial)[((size_t)b * SEGS + seg) * 32 + q] = t;
    }
}

// ---------------------------------------------------------------------------
// Kernel 3: per-graph block — reduce 16 seg partials -> pooled[H], then
// relu(pooled@W1+b1)@W2+b2 -> out[b][7]. 16 blocks x 128 threads.
// (r1 lesson: last-block-done fusion costs ~19 µs via device-scope
// threadfence on non-coherent XCD L2s. Separate tiny launch is cheaper.)
// ---------------------------------------------------------------------------
__global__ __launch_bounds__(128) void k_mlp(const float* __restrict__ partial,
                                             const float* __restrict__ W1,
                                             const float* __restrict__ b1,
                                             const float* __restrict__ W2,
                                             const float* __restrict__ b2,
                                             float* __restrict__ out) {
    __shared__ float pooled[H_DIM];
    __shared__ float h1[H_DIM];
    const int b = blockIdx.x;
    const int j = threadIdx.x;

    float s = 0.0f;
#pragma unroll
    for (int g = 0; g < SEGS; ++g)
        s += partial[((size_t)b * SEGS + g) * H_DIM + j];
    pooled[j] = s;
    __syncthreads();

    float acc = b1[j];
#pragma unroll 8
    for (int hh = 0; hh < H_DIM; ++hh)
        acc = fmaf(pooled[hh], W1[hh * H_DIM + j], acc);
    h1[j] = fmaxf(acc, 0.0f);
    __syncthreads();

    if (j < C_OUT) {
        float o = b2[j];
#pragma unroll 8
        for (int hh = 0; hh < H_DIM; ++hh)
            o = fmaf(h1[hh], W2[hh * C_OUT + j], o);
        out[(size_t)b * C_OUT + j] = o;
    }
}

extern "C" void kernel_launch(void* const* d_in, const int* in_sizes, int n_in,
                              void* d_out, int out_size, void* d_ws, size_t ws_size,
                              hipStream_t stream) {
    const float* verts  = (const float*)d_in[0];   // [B,V,3]
    const float* coords = (const float*)d_in[1];   // [B,N,3]
    const float* feats  = (const float*)d_in[2];   // [B,N,H]
    const float* W1     = (const float*)d_in[3];   // [H,H]
    const float* b1     = (const float*)d_in[4];   // [H]
    const float* W2     = (const float*)d_in[5];   // [H,C_OUT]
    const float* b2     = (const float*)d_in[6];   // [C_OUT]
    float* out = (float*)d_out;                    // [B,C_OUT]

    // workspace layout (pruned path, ~2.9 MB total)
    const size_t vf4_bytes  = (size_t)B_GR * V_PTS * 16;   // 2 MB (16B aligned @0)
    const size_t sf4_bytes  = (size_t)B_GR * N_RES * 16;   // 512 KB
    const size_t sidx_bytes = (size_t)B_GR * N_RES * 4;    // 128 KB
    const size_t cell_bytes = (size_t)B_GR * CPAD * 4;     // ~33 KB
    const size_t msk_bytes  = (size_t)B_GR * N_RES * 4;    // 128 KB
    const size_t pp_bytes   = (size_t)B_GR * SEGS * H_DIM * 4; // 128 KB
    const size_t need = vf4_bytes + sf4_bytes + sidx_bytes + cell_bytes + msk_bytes + pp_bytes;

    if (ws_size >= need) {
        char* p = (char*)d_ws;
        float4*       vf4g  = (float4*)p;                      p += vf4_bytes;
        float4*       sf4g  = (float4*)p;                      p += sf4_bytes;
        unsigned int* sidxg = (unsigned int*)p;                p += sidx_bytes;
        unsigned int* cells = (unsigned int*)p;                p += cell_bytes;
        float*        msk   = (float*)p;                       p += msk_bytes;
        float*        partial = (float*)p;

        k_prep  <<<B_GR,               256, 0, stream>>>(coords, verts, sf4g, sidxg,
                                                         cells, vf4g, msk);
        k_search<<<B_GR * V_PTS / 256, 256, 0, stream>>>(vf4g, sf4g, sidxg, cells, msk);
        k_pool_m<<<B_GR * SEGS,        256, 0, stream>>>(msk, feats, partial);
        k_mlp   <<<B_GR,               128, 0, stream>>>(partial, W1, b1, W2, b2, out);
    } else {
        // ---- fallback: brute-force atomicMin path ----
        unsigned long long* mi64 = (unsigned long long*)d_ws;              // 1 MB
        float* partial = (float*)((char*)d_ws + (size_t)B_GR * V_PTS * 8); // 128 KB

        hipMemsetAsync(mi64, 0xFF, (size_t)B_GR * V_PTS * 8, stream);
        k_argmin_at<<<B_GR * FVBLKS * NSPLIT, 256, 0, stream>>>(verts, coords, mi64);
        k_pool_at  <<<B_GR * SEGS,            256, 0, stream>>>(mi64, feats, partial);
        k_mlp      <<<B_GR,                   128, 0, stream>>>(partial, W1, b1, W2, b2, out);
    }
}